// Round 5
// baseline (303.024 us; speedup 1.0000x reference)
//
#include <hip/hip_runtime.h>
#include <stdint.h>

typedef unsigned short u16;
typedef __bf16 bfx8 __attribute__((ext_vector_type(8)));
typedef float f32x4 __attribute__((ext_vector_type(4)));

#define HD 768
#define NTREE 40000
#define NCODES 10000
#define GNN 1536
#define OUTD 512
#define NBV 512
#define VNEG (-1e30f)
#define TB 4

// GEMM tiling: 256x256 tile, BK=64, 8 waves as 2M x 4N (128x64 per wave),
// 4 phases per K-tile, frag-reads pipelined ONE PHASE AHEAD (counted lgkmcnt).
#define BM 256
#define BN 256
#define BK 64
#define NKT (HD / BK)                // 12
#define NMT ((NTREE + BM - 1) / BM)  // 157
#define NNT (GNN / BN)               // 6
#define GRID (NMT * NNT)             // 942
#define Q8 (GRID / 8)                // 117
#define R8 (GRID % 8)                // 6

#define WAITV(n) asm volatile("s_waitcnt vmcnt(" #n ")" ::: "memory")
#define LGKM(n)  asm volatile("s_waitcnt lgkmcnt(" #n ")" ::: "memory")

__device__ __forceinline__ float bf2f(u16 u) {
  union { uint32_t i; float f; } v; v.i = ((uint32_t)u) << 16; return v.f;
}
__device__ __forceinline__ u16 f2bf(float f) {
  union { float fl; uint32_t i; } v; v.fl = f;
  uint32_t u = v.i;
  u += 0x7FFFu + ((u >> 16) & 1u);
  return (u16)(u >> 16);
}

// ---------------- K0a: fp32 -> bf16 convert of embed table ----------------
__global__ void k_convE(const float* __restrict__ E, u16* __restrict__ Ebf, int n4) {
  int i = blockIdx.x * blockDim.x + threadIdx.x;
  if (i >= n4) return;
  float4 v = ((const float4*)E)[i];
  ushort4 r;
  r.x = f2bf(v.x); r.y = f2bf(v.y); r.z = f2bf(v.z); r.w = f2bf(v.w);
  ((ushort4*)Ebf)[i] = r;
}

// ---------------- K0b: build Bt[n][k] (bf16) from w1 (1536x768 row-major) --
__global__ void k_bt(const float* __restrict__ w1, u16* __restrict__ Bt) {
  int idx = blockIdx.x * blockDim.x + threadIdx.x;
  if (idx >= GNN * HD) return;
  int n = idx / HD, k = idx % HD;
  int srow = k + ((n >= HD) ? HD : 0);
  int scol = (n >= HD) ? (n - HD) : n;
  Bt[idx] = f2bf(w1[(size_t)srow * HD + scol]);
}

// ---------------- K1: bf16 MFMA GEMM  PQ[40000][1536] = Ebf @ B -----------
// LDS byte map: A buf b at b*32768; B buf b at 65536 + b*32768.
// Row r at r*128 bytes; 16B chunk phys = logical ^ (r&7) (both-sides swizzle).
__global__ __launch_bounds__(512, 2) void k_gemm(const u16* __restrict__ A,
                                                 const u16* __restrict__ B,
                                                 u16* __restrict__ C) {
  __shared__ u16 lds[65536];  // 128 KB

  const int tid    = threadIdx.x;
  const int lane   = tid & 63;
  const int wv     = tid >> 6;       // 0..7
  const int wm     = wv >> 2;        // 0..1: wave's M half (rows wm*128..+127)
  const int wn2    = wv & 3;         // 0..3: wave's N strip (cols wn2*64..+63)
  const int lane15 = lane & 15;
  const int g      = lane >> 4;      // 0..3: 16B chunk within K=32 step

  // bijective XCD swizzle, nt-minor (blocks on one XCD share the A panel)
  const int orig = blockIdx.x;
  const int xcd = orig & 7, lin = orig >> 3;
  const int wg = (xcd < R8 ? xcd * (Q8 + 1) : R8 * (Q8 + 1) + (xcd - R8) * Q8) + lin;
  const int mt = wg / NNT, nt = wg % NNT;
  const int tm = mt * BM, tn = nt * BN;

  // staging source offsets (u16 elements; pre-swizzled global source, rule 21)
  uint32_t aOff[2][2], bOff[2][2];  // [u][half]
#pragma unroll
  for (int u = 0; u < 2; ++u) {
    const int o    = u * 8192 + tid * 16;          // byte in 16KB half
    const int rloc = o >> 7;                        // local row 0..127
    const int c    = ((o >> 4) & 7) ^ (rloc & 7);   // logical 16B chunk
#pragma unroll
    for (int h = 0; h < 2; ++h) {
      int ra = tm + h * 128 + rloc; if (ra > NTREE - 1) ra = NTREE - 1;
      aOff[u][h] = (uint32_t)ra * HD + c * 8;
      bOff[u][h] = (uint32_t)(tn + h * 128 + rloc) * HD + c * 8;
    }
  }

#define STAGE_A(MH, NB, TT) do {                                               \
    _Pragma("unroll") for (int u = 0; u < 2; ++u)                              \
      __builtin_amdgcn_global_load_lds(                                        \
        (const __attribute__((address_space(1))) void*)(A + aOff[u][MH] + (TT) * BK), \
        (__attribute__((address_space(3))) void*)((char*)lds + (NB) * 32768 +  \
            (MH) * 16384 + u * 8192 + tid * 16),                               \
        16, 0, 0);                                                             \
  } while (0)

#define STAGE_B(NH, NB, TT) do {                                               \
    _Pragma("unroll") for (int u = 0; u < 2; ++u)                              \
      __builtin_amdgcn_global_load_lds(                                        \
        (const __attribute__((address_space(1))) void*)(B + bOff[u][NH] + (TT) * BK), \
        (__attribute__((address_space(3))) void*)((char*)lds + 65536 +         \
            (NB) * 32768 + (NH) * 16384 + u * 8192 + tid * 16),                \
        16, 0, 0);                                                             \
  } while (0)

  f32x4 acc[8][4];
#pragma unroll
  for (int i = 0; i < 8; ++i)
#pragma unroll
    for (int j = 0; j < 4; ++j) acc[i][j] = (f32x4){0.f, 0.f, 0.f, 0.f};

  // swizzled read column offset (u16 elems) per k-step; row&7 == lane15&7
  int colz[2];
  colz[0] = ((0 * 4 + g) ^ (lane15 & 7)) * 8;
  colz[1] = ((1 * 4 + g) ^ (lane15 & 7)) * 8;
  const int aBase = (wm * 128 + lane15) * 64;  // u16 elems, row stride 64
  const int bBase = (wn2 * 64 + lane15) * 64;

  bfx8 aF0[4], aF1[4], bF0[4], bF1[4];  // named ping-pong frag buffers

#define READ_A(DST, MH, KS, BA) do {                                           \
    const int _a = (BA) + aBase + (MH) * 4096 + colz[KS];                      \
    _Pragma("unroll") for (int i = 0; i < 4; ++i)                              \
      DST[i] = *(const bfx8*)&lds[_a + i * 1024];                              \
  } while (0)

#define READ_B(DST, KS, BB) do {                                               \
    const int _b = (BB) + bBase + colz[KS];                                    \
    _Pragma("unroll") for (int j = 0; j < 4; ++j)                              \
      DST[j] = *(const bfx8*)&lds[_b + j * 1024];                              \
  } while (0)

#define MFMA16(MH, AFR, BFR) do {                                              \
    __builtin_amdgcn_s_setprio(1);                                             \
    _Pragma("unroll") for (int i = 0; i < 4; ++i)                              \
      _Pragma("unroll") for (int j = 0; j < 4; ++j)                            \
        acc[(MH) * 4 + i][j] = __builtin_amdgcn_mfma_f32_16x16x32_bf16(        \
            AFR[i], BFR[j], acc[(MH) * 4 + i][j], 0, 0, 0);                    \
    __builtin_amdgcn_s_setprio(0);                                             \
  } while (0)

  // prologue: stage tile 0 into buf 0, drain, barrier, prefetch p0 frags
  STAGE_A(0, 0, 0);
  STAGE_A(1, 0, 0);
  STAGE_B(0, 0, 0);
  STAGE_B(1, 0, 0);
  WAITV(0);
  __builtin_amdgcn_s_barrier();
  READ_A(aF0, 0, 0, 0);        // tile0 A-lo ks0 (4 reads, left in flight)
  READ_B(bF0, 0, 32768);       // tile0 B ks0   (4 reads, left in flight)

  for (int t = 0; t < NKT; ++t) {
    const int bA  = (t & 1) * 16384;          // u16 index of A buf (tile t)
    const int bB  = 32768 + (t & 1) * 16384;  // u16 index of B buf (tile t)
    const int nb  = (t + 1) & 1;
    const int nbA = nb * 16384;
    const int nbB = 32768 + nb * 16384;
    const bool more = (t + 1 < NKT);

    // ---- p0: MFMA (A-lo, ks0); prefetch A-hi ks0; stage A(t+1) ----
    READ_A(aF1, 1, 0, bA);
    if (more) { STAGE_A(0, nb, t + 1); STAGE_A(1, nb, t + 1); }
    LGKM(4);                                  // prologue/p3 reads (8) done
    __builtin_amdgcn_sched_barrier(0);
    MFMA16(0, aF0, bF0);
    __builtin_amdgcn_s_barrier();

    // ---- p1: MFMA (A-hi, ks0); prefetch A-lo ks1 + B ks1; stage B(t+1) ----
    READ_A(aF0, 0, 1, bA);
    READ_B(bF1, 1, bB);
    if (more) { STAGE_B(0, nb, t + 1); STAGE_B(1, nb, t + 1); }
    LGKM(8);                                  // p0's 4 done
    __builtin_amdgcn_sched_barrier(0);
    MFMA16(1, aF1, bF0);
    __builtin_amdgcn_s_barrier();

    // ---- p2: MFMA (A-lo, ks1); prefetch A-hi ks1; drain own stage writes ----
    READ_A(aF1, 1, 1, bA);
    LGKM(4);                                  // p1's 8 done
    __builtin_amdgcn_sched_barrier(0);
    MFMA16(0, aF0, bF1);
    WAITV(0);                                 // own 8 stage-writes drained
    __builtin_amdgcn_s_barrier();             // => buf t+1 fully staged (all waves)

    // ---- p3: MFMA (A-hi, ks1); prefetch tile-t+1 p0 frags across boundary ----
    if (more) {
      READ_A(aF0, 0, 0, nbA);
      READ_B(bF0, 0, nbB);
      LGKM(8);                                // p2's 4 done
    } else {
      LGKM(0);
    }
    __builtin_amdgcn_sched_barrier(0);
    MFMA16(1, aF1, bF1);
    __builtin_amdgcn_s_barrier();
  }

  // epilogue: D row = (lane>>4)*4 + rr (M side), col = lane&15 (N side)
  const int r0 = (lane >> 4) * 4, cc = lane15;
#pragma unroll
  for (int mf = 0; mf < 8; ++mf) {
#pragma unroll
    for (int nf = 0; nf < 4; ++nf) {
#pragma unroll
      for (int rr = 0; rr < 4; ++rr) {
        const int row = tm + wm * 128 + mf * 16 + r0 + rr;
        if (row < NTREE) {
          const int col = tn + wn2 * 64 + nf * 16 + cc;
          C[(size_t)row * GNN + col] = f2bf(acc[mf][nf][rr]);
        }
      }
    }
  }
#undef MFMA16
#undef READ_A
#undef READ_B
#undef STAGE_A
#undef STAGE_B
}

// ---------------- K2: scores + masked softmax + dag_emb -------------------
// 8 waves, one (n,a) pair per wave; all 64 lanes in the score dot (12 elems
// each); masked pairs skipped entirely.
__global__ __launch_bounds__(512) void k_attn(const u16* __restrict__ PQ,
                                              const u16* __restrict__ Ebf,
                                              const float* __restrict__ b1,
                                              const float* __restrict__ w2,
                                              const float* __restrict__ b2,
                                              const float* __restrict__ masks,
                                              const int* __restrict__ leaves,
                                              const int* __restrict__ anc,
                                              float* __restrict__ dag) {
  const int n = blockIdx.x;
  const int tid = threadIdx.x, lane = tid & 63, wv = tid >> 6;
  __shared__ float sc[8];
  __shared__ float m_s[8];
  __shared__ int   an_s[8];
  __shared__ int   lv_s[8];
  if (tid < 8) {
    an_s[tid] = anc[n * 8 + tid];
    lv_s[tid] = leaves[n * 8 + tid];
    m_s[tid]  = masks[n * 8 + tid];
  }
  __syncthreads();

  {
    const int a = wv;
    const float mm = m_s[a];
    if (mm == 0.f) {
      if (lane == 0) sc[a] = VNEG;
    } else {
      const int l = lv_s[a], an = an_s[a];
      const u16* pr = PQ + (size_t)l * GNN;        // P part (cols 0..767)
      const u16* qr = PQ + (size_t)an * GNN + HD;  // Q part (cols 768..1535)
      const int d0 = lane * 12;
      float s = 0.f;
#pragma unroll
      for (int jj = 0; jj < 3; ++jj) {
        const int d = d0 + jj * 4;
        ushort4 pv = *(const ushort4*)(pr + d);
        ushort4 qv = *(const ushort4*)(qr + d);
        float4  bb = *(const float4*)(b1 + d);
        float4  ww = *(const float4*)(w2 + d);
        float v;
        v = fmaxf(bf2f(pv.x) + bf2f(qv.x) + bb.x, 0.f); s += v * ww.x;
        v = fmaxf(bf2f(pv.y) + bf2f(qv.y) + bb.y, 0.f); s += v * ww.y;
        v = fmaxf(bf2f(pv.z) + bf2f(qv.z) + bb.z, 0.f); s += v * ww.z;
        v = fmaxf(bf2f(pv.w) + bf2f(qv.w) + bb.w, 0.f); s += v * ww.w;
      }
#pragma unroll
      for (int off = 32; off > 0; off >>= 1) s += __shfl_down(s, off);
      if (lane == 0) sc[a] = s + b2[0];
    }
  }
  __syncthreads();

  float mx = sc[0];
#pragma unroll
  for (int a = 1; a < 8; ++a) mx = fmaxf(mx, sc[a]);
  float ex[8], den = 0.f;
#pragma unroll
  for (int a = 0; a < 8; ++a) { ex[a] = expf(sc[a] - mx); den += ex[a]; }
  const float inv = 1.0f / den;
  float cf[8];
#pragma unroll
  for (int a = 0; a < 8; ++a) cf[a] = ex[a] * inv * m_s[a];

  {
    const int d = tid;
    float accv = 0.f;
#pragma unroll
    for (int a = 0; a < 8; ++a) {
      const float cfa = cf[a];
      if (cfa != 0.f) accv += cfa * bf2f(Ebf[(size_t)an_s[a] * HD + d]);
    }
    dag[(size_t)n * HD + d] = accv;
  }
  if (tid < 256) {
    const int d = 512 + tid;
    float accv = 0.f;
#pragma unroll
    for (int a = 0; a < 8; ++a) {
      const float cfa = cf[a];
      if (cfa != 0.f) accv += cfa * bf2f(Ebf[(size_t)an_s[a] * HD + d]);
    }
    dag[(size_t)n * HD + d] = accv;
  }
}

// ---------------- K3: gather dict + masked mean pooling (float4) ----------
__global__ __launch_bounds__(256) void k_pool(const float* __restrict__ dag,
                                              const int* __restrict__ ids,
                                              const float* __restrict__ cm,
                                              float* __restrict__ pooled) {
  const int bv = blockIdx.x, tid = threadIdx.x;
  __shared__ int   id_s[48];
  __shared__ float cm_s[48];
  if (tid < 48) { id_s[tid] = ids[bv * 48 + tid]; cm_s[tid] = cm[bv * 48 + tid]; }
  __syncthreads();
  float cnt = 0.f;
  for (int m = 0; m < 48; ++m) cnt += cm_s[m];
  const float scale = 1.0f / fmaxf(cnt, 1.0f);
  if (tid < 192) {
    float4 accv = make_float4(0.f, 0.f, 0.f, 0.f);
    for (int m = 0; m < 48; ++m) {
      const int id = id_s[m];
      const float cv = cm_s[m];
      if (id > 0 && cv != 0.f) {
        float4 v = *(const float4*)(dag + (size_t)(id - 1) * HD + tid * 4);
        accv.x += cv * v.x; accv.y += cv * v.y;
        accv.z += cv * v.z; accv.w += cv * v.w;
      }
    }
    accv.x *= scale; accv.y *= scale; accv.z *= scale; accv.w *= scale;
    *(float4*)(pooled + (size_t)bv * HD + tid * 4) = accv;
  }
}

// ---------------- K4: out = pooled @ wc + bc ------------------------------
__global__ __launch_bounds__(256) void k_out(const float* __restrict__ pooled,
                                             const float* __restrict__ wc,
                                             const float* __restrict__ bc,
                                             float* __restrict__ out) {
  const int b0 = blockIdx.x * TB;
  const int tid = threadIdx.x;
  __shared__ float pl[TB][HD];
  for (int i = tid; i < TB * HD; i += 256) pl[i / HD][i % HD] = pooled[(size_t)b0 * HD + i];
  __syncthreads();
  float a0[TB], a1[TB];
#pragma unroll
  for (int r = 0; r < TB; ++r) { a0[r] = 0.f; a1[r] = 0.f; }
  for (int h = 0; h < HD; ++h) {
    const float w0  = wc[(size_t)h * OUTD + tid];
    const float w1v = wc[(size_t)h * OUTD + tid + 256];
#pragma unroll
    for (int r = 0; r < TB; ++r) { const float p = pl[r][h]; a0[r] += p * w0; a1[r] += p * w1v; }
  }
  const float bc0 = bc[tid], bc1 = bc[tid + 256];
#pragma unroll
  for (int r = 0; r < TB; ++r) {
    out[(size_t)(b0 + r) * OUTD + tid]       = a0[r] + bc0;
    out[(size_t)(b0 + r) * OUTD + tid + 256] = a1[r] + bc1;
  }
}

extern "C" void kernel_launch(void* const* d_in, const int* in_sizes, int n_in,
                              void* d_out, int out_size, void* d_ws, size_t ws_size,
                              hipStream_t stream) {
  const float* E     = (const float*)d_in[0];
  const float* w1    = (const float*)d_in[1];
  const float* b1    = (const float*)d_in[2];
  const float* w2    = (const float*)d_in[3];
  const float* b2    = (const float*)d_in[4];
  const float* wc    = (const float*)d_in[5];
  const float* bc    = (const float*)d_in[6];
  const float* masks = (const float*)d_in[7];
  const float* cm    = (const float*)d_in[8];
  const int*   leaves = (const int*)d_in[9];
  const int*   anc    = (const int*)d_in[10];
  const int*   ids    = (const int*)d_in[11];
  float* out = (float*)d_out;

  if (n_in < 12) return;
  if (in_sizes[0] != NTREE * HD) return;
  if (out_size != NBV * OUTD) return;

  char* ws = (char*)d_ws;
  const size_t szEbf = (size_t)NTREE * HD * 2;
  const size_t szBt  = (size_t)GNN * HD * 2;
  const size_t szPQ  = (size_t)NTREE * GNN * 2;
  const size_t szDag = (size_t)NCODES * HD * 4;
  const size_t szPl  = (size_t)NBV * HD * 4;
  if (ws_size < szEbf + szBt + szPQ + szDag + szPl) return;  // ~209 MB

  u16*   Ebf    = (u16*)ws;            ws += szEbf;
  u16*   Bt     = (u16*)ws;            ws += szBt;
  u16*   PQ     = (u16*)ws;            ws += szPQ;
  float* dag    = (float*)ws;          ws += szDag;
  float* pooled = (float*)ws;          ws += szPl;

  const int n4 = NTREE * HD / 4;
  k_convE<<<(n4 + 255) / 256, 256, 0, stream>>>(E, Ebf, n4);
  k_bt<<<(GNN * HD + 255) / 256, 256, 0, stream>>>(w1, Bt);
  k_gemm<<<GRID, 512, 0, stream>>>(Ebf, Bt, PQ);
  k_attn<<<NCODES, 512, 0, stream>>>(PQ, Ebf, b1, w2, b2, masks, leaves, anc, dag);
  k_pool<<<NBV, 256, 0, stream>>>(dag, ids, cm, pooled);
  k_out<<<NBV / TB, 256, 0, stream>>>(pooled, wc, bc, out);
}

// Round 6
// 287.169 us; speedup vs baseline: 1.0552x; 1.0552x over previous
//
#include <hip/hip_runtime.h>
#include <stdint.h>

typedef unsigned short u16;
typedef __bf16 bfx8 __attribute__((ext_vector_type(8)));
typedef float f32x4 __attribute__((ext_vector_type(4)));

#define HD 768
#define NTREE 40000
#define NCODES 10000
#define GNN 1536
#define OUTD 512
#define NBV 512
#define VNEG (-1e30f)
#define TB 4

// GEMM tiling: 256x256 tile, BK=32, 8 waves as 2M x 4N (128x64 per wave),
// 2 phases per K-tile, 4-deep LDS ring, counted vmcnt(8) (never full drain),
// frag reads one phase ahead (counted lgkmcnt), 2-row superrow swizzle.
#define BM 256
#define BN 256
#define BK2 32
#define NKT2 (HD / BK2)              // 24
#define NMT ((NTREE + BM - 1) / BM)  // 157
#define NNT (GNN / BN)               // 6
#define GRID (NMT * NNT)             // 942
#define Q8 (GRID / 8)                // 117
#define R8 (GRID % 8)                // 6

#define WAITV(n) asm volatile("s_waitcnt vmcnt(" #n ")" ::: "memory")
#define LGKM(n)  asm volatile("s_waitcnt lgkmcnt(" #n ")" ::: "memory")

__device__ __forceinline__ float bf2f(u16 u) {
  union { uint32_t i; float f; } v; v.i = ((uint32_t)u) << 16; return v.f;
}
__device__ __forceinline__ u16 f2bf(float f) {
  union { float fl; uint32_t i; } v; v.fl = f;
  uint32_t u = v.i;
  u += 0x7FFFu + ((u >> 16) & 1u);
  return (u16)(u >> 16);
}

// ---------------- K0: fused convE (fp32->bf16) + Bt build -----------------
#define NBLK_CONV 30000  // NTREE*HD/4/256
__global__ void k_prep(const float* __restrict__ E, u16* __restrict__ Ebf,
                       const float* __restrict__ w1, u16* __restrict__ Bt) {
  const int bid = blockIdx.x, tid = threadIdx.x;
  if (bid < NBLK_CONV) {
    const int i = bid * 256 + tid;  // < NTREE*HD/4
    float4 v = ((const float4*)E)[i];
    ushort4 r;
    r.x = f2bf(v.x); r.y = f2bf(v.y); r.z = f2bf(v.z); r.w = f2bf(v.w);
    ((ushort4*)Ebf)[i] = r;
  } else {
    const int idx = (bid - NBLK_CONV) * 256 + tid;
    if (idx < GNN * HD) {
      const int n = idx / HD, k = idx % HD;
      const int srow = k + ((n >= HD) ? HD : 0);
      const int scol = (n >= HD) ? (n - HD) : n;
      Bt[idx] = f2bf(w1[(size_t)srow * HD + scol]);
    }
  }
}

// ---------------- K1: bf16 MFMA GEMM  PQ[40000][1536] = Ebf @ B -----------
// LDS: A ring buf b at u16 b*8192 (16KB each); B at 32768 + b*8192. 128KB.
// Superrow layout: unit idx (0..1023) = s*8+phys; slot = phys^(s&7);
// row = 2s + (slot>>2), k-chunk = slot&3. Both-sides involution.
__global__ __launch_bounds__(512, 2) void k_gemm(const u16* __restrict__ A,
                                                 const u16* __restrict__ B,
                                                 u16* __restrict__ C) {
  __shared__ u16 lds[65536];  // 128 KB

  const int tid    = threadIdx.x;
  const int lane   = tid & 63;
  const int wv     = tid >> 6;       // 0..7
  const int wm     = wv >> 2;        // 0..1: wave's M half (rows wm*128..+127)
  const int wn2    = wv & 3;         // 0..3: wave's N strip (cols wn2*64..+63)
  const int lane15 = lane & 15;
  const int g      = lane >> 4;      // 0..3: 16B k-chunk within K=32

  // bijective XCD swizzle, nt-minor (blocks on one XCD share the A panel)
  const int orig = blockIdx.x;
  const int xcd = orig & 7, lin = orig >> 3;
  const int wg = (xcd < R8 ? xcd * (Q8 + 1) : R8 * (Q8 + 1) + (xcd - R8) * Q8) + lin;
  const int mt = wg / NNT, nt = wg % NNT;
  const int tm = mt * BM, tn = nt * BN;

  // staging source offsets (u16 elems; inverse-swizzled global source)
  uint32_t aOff[2], bOff[2];
#pragma unroll
  for (int u = 0; u < 2; ++u) {
    const int idx  = u * 512 + tid;            // 16B unit 0..1023
    const int s    = idx >> 3;                 // superrow 0..127
    const int phys = idx & 7;
    const int slot = phys ^ (s & 7);
    const int row  = 2 * s + (slot >> 2);
    const int chnk = slot & 3;
    int ra = tm + row; if (ra > NTREE - 1) ra = NTREE - 1;
    aOff[u] = (uint32_t)ra * HD + chnk * 8;
    bOff[u] = (uint32_t)(tn + row) * HD + chnk * 8;
  }

#define STAGE(TT) do {                                                         \
    const int _b = ((TT) & 3);                                                 \
    _Pragma("unroll") for (int u = 0; u < 2; ++u) {                            \
      __builtin_amdgcn_global_load_lds(                                        \
        (const __attribute__((address_space(1))) void*)(A + aOff[u] + (TT) * BK2), \
        (__attribute__((address_space(3))) void*)((char*)lds + _b * 16384 +    \
            u * 8192 + tid * 16), 16, 0, 0);                                   \
      __builtin_amdgcn_global_load_lds(                                        \
        (const __attribute__((address_space(1))) void*)(B + bOff[u] + (TT) * BK2), \
        (__attribute__((address_space(3))) void*)((char*)lds + 65536 +         \
            _b * 16384 + u * 8192 + tid * 16), 16, 0, 0);                      \
    }                                                                          \
  } while (0)

  f32x4 acc[8][4];
#pragma unroll
  for (int i = 0; i < 8; ++i)
#pragma unroll
    for (int j = 0; j < 4; ++j) acc[i][j] = (f32x4){0.f, 0.f, 0.f, 0.f};

  // per-lane frag read offsets (u16 elems): row R -> s=R>>1,
  // slot=((R&1)<<2)|g, phys=slot^(s&7), off = s*64 + phys*8
  int aIdx[8], bIdx[4];
#pragma unroll
  for (int mf = 0; mf < 8; ++mf) {
    const int R = wm * 128 + mf * 16 + lane15;
    const int s = R >> 1, slot = ((R & 1) << 2) | g, phys = slot ^ (s & 7);
    aIdx[mf] = s * 64 + phys * 8;
  }
#pragma unroll
  for (int nf = 0; nf < 4; ++nf) {
    const int R = wn2 * 64 + nf * 16 + lane15;
    const int s = R >> 1, slot = ((R & 1) << 2) | g, phys = slot ^ (s & 7);
    bIdx[nf] = s * 64 + phys * 8;
  }

  bfx8 aX[4], aY[4], bE[4], bO[4];

#define MFMA4x4(ACC0, AFR, BFR) do {                                           \
    __builtin_amdgcn_s_setprio(1);                                             \
    _Pragma("unroll") for (int i = 0; i < 4; ++i)                              \
      _Pragma("unroll") for (int j = 0; j < 4; ++j)                            \
        acc[(ACC0) + i][j] = __builtin_amdgcn_mfma_f32_16x16x32_bf16(          \
            AFR[i], BFR[j], acc[(ACC0) + i][j], 0, 0, 0);                      \
    __builtin_amdgcn_s_setprio(0);                                             \
  } while (0)

// tile body: ph0 {read aY | stage t+3 | lgkm(4) | MFMA q0(aX,BCUR) | bar}
//            ph1 {vmcnt(8) | cross-read aX,BNXT of t+1 | lgkm(8) |
//                 MFMA q1(aY,BCUR) | bar}
#define TILE(T, BCUR, BNXT) {                                                  \
    const int bufA = ((T) & 3) * 8192;                                         \
    _Pragma("unroll") for (int i = 0; i < 4; ++i)                              \
      aY[i] = *(const bfx8*)&lds[bufA + aIdx[4 + i]];                          \
    if ((T) + 3 < NKT2) STAGE((T) + 3);                                        \
    LGKM(4);                                                                   \
    __builtin_amdgcn_sched_barrier(0);                                         \
    MFMA4x4(0, aX, BCUR);                                                      \
    __builtin_amdgcn_s_barrier();                                              \
    if ((T) < NKT2 - 1) {                                                      \
      if ((T) <= NKT2 - 4)      { WAITV(8); }                                  \
      else if ((T) == NKT2 - 3) { WAITV(4); }                                  \
      else                      { WAITV(0); }                                  \
      const int nA = (((T) + 1) & 3) * 8192;                                   \
      const int nB = 32768 + (((T) + 1) & 3) * 8192;                           \
      _Pragma("unroll") for (int i = 0; i < 4; ++i)                            \
        aX[i] = *(const bfx8*)&lds[nA + aIdx[i]];                              \
      _Pragma("unroll") for (int j = 0; j < 4; ++j)                            \
        BNXT[j] = *(const bfx8*)&lds[nB + bIdx[j]];                            \
      LGKM(8);                                                                 \
    } else { LGKM(0); }                                                        \
    __builtin_amdgcn_sched_barrier(0);                                         \
    MFMA4x4(4, aY, BCUR);                                                      \
    __builtin_amdgcn_s_barrier();                                              \
  }

  // prologue: stage tiles 0..2 (12 loads), wait tile0 (leave 8), read t0 frags
  STAGE(0);
  STAGE(1);
  STAGE(2);
  WAITV(8);
  __builtin_amdgcn_s_barrier();
#pragma unroll
  for (int i = 0; i < 4; ++i) aX[i] = *(const bfx8*)&lds[aIdx[i]];
#pragma unroll
  for (int j = 0; j < 4; ++j) bE[j] = *(const bfx8*)&lds[32768 + bIdx[j]];

  for (int t2 = 0; t2 < NKT2; t2 += 2) {
    TILE(t2, bE, bO);
    TILE(t2 + 1, bO, bE);
  }

  // epilogue: D row = (lane>>4)*4 + rr (M side), col = lane&15 (N side)
  const int r0 = (lane >> 4) * 4, cc = lane15;
#pragma unroll
  for (int mf = 0; mf < 8; ++mf) {
#pragma unroll
    for (int nf = 0; nf < 4; ++nf) {
#pragma unroll
      for (int rr = 0; rr < 4; ++rr) {
        const int row = tm + wm * 128 + mf * 16 + r0 + rr;
        if (row < NTREE) {
          const int col = tn + wn2 * 64 + nf * 16 + cc;
          C[(size_t)row * GNN + col] = f2bf(acc[mf][nf][rr]);
        }
      }
    }
  }
#undef TILE
#undef MFMA4x4
#undef STAGE
}

// ---------------- K2: scores + masked softmax + dag_emb -------------------
__global__ __launch_bounds__(512) void k_attn(const u16* __restrict__ PQ,
                                              const u16* __restrict__ Ebf,
                                              const float* __restrict__ b1,
                                              const float* __restrict__ w2,
                                              const float* __restrict__ b2,
                                              const float* __restrict__ masks,
                                              const int* __restrict__ leaves,
                                              const int* __restrict__ anc,
                                              float* __restrict__ dag) {
  const int n = blockIdx.x;
  const int tid = threadIdx.x, lane = tid & 63, wv = tid >> 6;
  __shared__ float sc[8];
  __shared__ float m_s[8];
  __shared__ int   an_s[8];
  __shared__ int   lv_s[8];
  if (tid < 8) {
    an_s[tid] = anc[n * 8 + tid];
    lv_s[tid] = leaves[n * 8 + tid];
    m_s[tid]  = masks[n * 8 + tid];
  }
  __syncthreads();

  {
    const int a = wv;
    const float mm = m_s[a];
    if (mm == 0.f) {
      if (lane == 0) sc[a] = VNEG;
    } else {
      const int l = lv_s[a], an = an_s[a];
      const u16* pr = PQ + (size_t)l * GNN;        // P part (cols 0..767)
      const u16* qr = PQ + (size_t)an * GNN + HD;  // Q part (cols 768..1535)
      const int d0 = lane * 12;
      float s = 0.f;
#pragma unroll
      for (int jj = 0; jj < 3; ++jj) {
        const int d = d0 + jj * 4;
        ushort4 pv = *(const ushort4*)(pr + d);
        ushort4 qv = *(const ushort4*)(qr + d);
        float4  bb = *(const float4*)(b1 + d);
        float4  ww = *(const float4*)(w2 + d);
        float v;
        v = fmaxf(bf2f(pv.x) + bf2f(qv.x) + bb.x, 0.f); s += v * ww.x;
        v = fmaxf(bf2f(pv.y) + bf2f(qv.y) + bb.y, 0.f); s += v * ww.y;
        v = fmaxf(bf2f(pv.z) + bf2f(qv.z) + bb.z, 0.f); s += v * ww.z;
        v = fmaxf(bf2f(pv.w) + bf2f(qv.w) + bb.w, 0.f); s += v * ww.w;
      }
#pragma unroll
      for (int off = 32; off > 0; off >>= 1) s += __shfl_down(s, off);
      if (lane == 0) sc[a] = s + b2[0];
    }
  }
  __syncthreads();

  float mx = sc[0];
#pragma unroll
  for (int a = 1; a < 8; ++a) mx = fmaxf(mx, sc[a]);
  float ex[8], den = 0.f;
#pragma unroll
  for (int a = 0; a < 8; ++a) { ex[a] = expf(sc[a] - mx); den += ex[a]; }
  const float inv = 1.0f / den;
  float cf[8];
#pragma unroll
  for (int a = 0; a < 8; ++a) cf[a] = ex[a] * inv * m_s[a];

  if (tid < 384) {
    const int d = tid * 2;
    float a0 = 0.f, a1 = 0.f;
#pragma unroll
    for (int a = 0; a < 8; ++a) {
      const float cfa = cf[a];
      if (cfa != 0.f) {
        const uint32_t w = *(const uint32_t*)(Ebf + (size_t)an_s[a] * HD + d);
        a0 += cfa * bf2f((u16)(w & 0xffffu));
        a1 += cfa * bf2f((u16)(w >> 16));
      }
    }
    float2 r; r.x = a0; r.y = a1;
    *(float2*)(dag + (size_t)n * HD + d) = r;
  }
}

// ---------------- K3: gather dict + masked mean pooling (float4) ----------
__global__ __launch_bounds__(256) void k_pool(const float* __restrict__ dag,
                                              const int* __restrict__ ids,
                                              const float* __restrict__ cm,
                                              float* __restrict__ pooled) {
  const int bv = blockIdx.x, tid = threadIdx.x;
  __shared__ int   id_s[48];
  __shared__ float cm_s[48];
  if (tid < 48) { id_s[tid] = ids[bv * 48 + tid]; cm_s[tid] = cm[bv * 48 + tid]; }
  __syncthreads();
  float cnt = 0.f;
  for (int m = 0; m < 48; ++m) cnt += cm_s[m];
  const float scale = 1.0f / fmaxf(cnt, 1.0f);
  if (tid < 192) {
    float4 accv = make_float4(0.f, 0.f, 0.f, 0.f);
    for (int m = 0; m < 48; ++m) {
      const int id = id_s[m];
      const float cv = cm_s[m];
      if (id > 0 && cv != 0.f) {
        float4 v = *(const float4*)(dag + (size_t)(id - 1) * HD + tid * 4);
        accv.x += cv * v.x; accv.y += cv * v.y;
        accv.z += cv * v.z; accv.w += cv * v.w;
      }
    }
    accv.x *= scale; accv.y *= scale; accv.z *= scale; accv.w *= scale;
    *(float4*)(pooled + (size_t)bv * HD + tid * 4) = accv;
  }
}

// ---------------- K4: out = pooled @ wc + bc ------------------------------
__global__ __launch_bounds__(256) void k_out(const float* __restrict__ pooled,
                                             const float* __restrict__ wc,
                                             const float* __restrict__ bc,
                                             float* __restrict__ out) {
  const int b0 = blockIdx.x * TB;
  const int tid = threadIdx.x;
  __shared__ float pl[TB][HD];
  for (int i = tid; i < TB * HD; i += 256) pl[i / HD][i % HD] = pooled[(size_t)b0 * HD + i];
  __syncthreads();
  float a0[TB], a1[TB];
#pragma unroll
  for (int r = 0; r < TB; ++r) { a0[r] = 0.f; a1[r] = 0.f; }
  for (int h = 0; h < HD; ++h) {
    const float w0  = wc[(size_t)h * OUTD + tid];
    const float w1v = wc[(size_t)h * OUTD + tid + 256];
#pragma unroll
    for (int r = 0; r < TB; ++r) { const float p = pl[r][h]; a0[r] += p * w0; a1[r] += p * w1v; }
  }
  const float bc0 = bc[tid], bc1 = bc[tid + 256];
#pragma unroll
  for (int r = 0; r < TB; ++r) {
    out[(size_t)(b0 + r) * OUTD + tid]       = a0[r] + bc0;
    out[(size_t)(b0 + r) * OUTD + tid + 256] = a1[r] + bc1;
  }
}

extern "C" void kernel_launch(void* const* d_in, const int* in_sizes, int n_in,
                              void* d_out, int out_size, void* d_ws, size_t ws_size,
                              hipStream_t stream) {
  const float* E     = (const float*)d_in[0];
  const float* w1    = (const float*)d_in[1];
  const float* b1    = (const float*)d_in[2];
  const float* w2    = (const float*)d_in[3];
  const float* b2    = (const float*)d_in[4];
  const float* wc    = (const float*)d_in[5];
  const float* bc    = (const float*)d_in[6];
  const float* masks = (const float*)d_in[7];
  const float* cm    = (const float*)d_in[8];
  const int*   leaves = (const int*)d_in[9];
  const int*   anc    = (const int*)d_in[10];
  const int*   ids    = (const int*)d_in[11];
  float* out = (float*)d_out;

  if (n_in < 12) return;
  if (in_sizes[0] != NTREE * HD) return;
  if (out_size != NBV * OUTD) return;

  char* ws = (char*)d_ws;
  const size_t szEbf = (size_t)NTREE * HD * 2;
  const size_t szBt  = (size_t)GNN * HD * 2;
  const size_t szPQ  = (size_t)NTREE * GNN * 2;
  const size_t szDag = (size_t)NCODES * HD * 4;
  const size_t szPl  = (size_t)NBV * HD * 4;
  if (ws_size < szEbf + szBt + szPQ + szDag + szPl) return;  // ~209 MB

  u16*   Ebf    = (u16*)ws;            ws += szEbf;
  u16*   Bt     = (u16*)ws;            ws += szBt;
  u16*   PQ     = (u16*)ws;            ws += szPQ;
  float* dag    = (float*)ws;          ws += szDag;
  float* pooled = (float*)ws;          ws += szPl;

  const int nPrep = NBLK_CONV + (GNN * HD + 255) / 256;
  k_prep<<<nPrep, 256, 0, stream>>>(E, Ebf, w1, Bt);
  k_gemm<<<GRID, 512, 0, stream>>>(Ebf, Bt, PQ);
  k_attn<<<NCODES, 512, 0, stream>>>(PQ, Ebf, b1, w2, b2, masks, leaves, anc, dag);
  k_pool<<<NBV, 256, 0, stream>>>(dag, ids, cm, pooled);
  k_out<<<NBV / TB, 256, 0, stream>>>(pooled, wc, bc, out);
}

// Round 7
// 276.982 us; speedup vs baseline: 1.0940x; 1.0368x over previous
//
#include <hip/hip_runtime.h>
#include <stdint.h>

typedef unsigned short u16;
typedef __bf16 bfx8 __attribute__((ext_vector_type(8)));
typedef float f32x4 __attribute__((ext_vector_type(4)));

#define HD 768
#define NTREE 40000
#define NCODES 10000
#define GNN 1536
#define OUTD 512
#define NBV 512
#define VNEG (-1e30f)
#define TB 4

// GEMM: 256x256 tile, BK=64, 8 waves (2x4 of 64x32 per quadrant),
// phase = one 128x128 C-quadrant x K=64; 1 half-tile staged per phase;
// counted WAITV(4) before phase barriers (never 0 in steady state).
#define BM 256
#define BN 256
#define BK 64
#define NKT (HD / BK)                // 12
#define NMT ((NTREE + BM - 1) / BM)  // 157
#define NNT (GNN / BN)               // 6
#define GRID (NMT * NNT)             // 942
#define Q8 (GRID / 8)                // 117
#define R8 (GRID % 8)                // 6

#define WAITV(n) asm volatile("s_waitcnt vmcnt(" #n ")" ::: "memory")
#define LGKM(n)  asm volatile("s_waitcnt lgkmcnt(" #n ")" ::: "memory")

__device__ __forceinline__ float bf2f(u16 u) {
  union { uint32_t i; float f; } v; v.i = ((uint32_t)u) << 16; return v.f;
}
__device__ __forceinline__ u16 f2bf(float f) {
  union { float fl; uint32_t i; } v; v.fl = f;
  uint32_t u = v.i;
  u += 0x7FFFu + ((u >> 16) & 1u);
  return (u16)(u >> 16);
}

// ---------------- K0: fused convE (fp32->bf16) + Bt build -----------------
#define NBLK_CONV 30000  // NTREE*HD/4/256
__global__ void k_prep(const float* __restrict__ E, u16* __restrict__ Ebf,
                       const float* __restrict__ w1, u16* __restrict__ Bt) {
  const int bid = blockIdx.x, tid = threadIdx.x;
  if (bid < NBLK_CONV) {
    const int i = bid * 256 + tid;
    float4 v = ((const float4*)E)[i];
    ushort4 r;
    r.x = f2bf(v.x); r.y = f2bf(v.y); r.z = f2bf(v.z); r.w = f2bf(v.w);
    ((ushort4*)Ebf)[i] = r;
  } else {
    const int idx = (bid - NBLK_CONV) * 256 + tid;
    if (idx < GNN * HD) {
      const int n = idx / HD, k = idx % HD;
      const int srow = k + ((n >= HD) ? HD : 0);
      const int scol = (n >= HD) ? (n - HD) : n;
      Bt[idx] = f2bf(w1[(size_t)srow * HD + scol]);
    }
  }
}

// ---------------- K1: bf16 MFMA GEMM  PQ[40000][1536] = Ebf @ B -----------
// LDS: A buf c at u16 c*16384 (32KB); B buf c at 32768 + c*16384. 128KB.
// Row r at r*128B; 16B chunk phys = logical ^ (r&7) (both-sides swizzle).
__global__ __launch_bounds__(512, 2) void k_gemm(const u16* __restrict__ A,
                                                 const u16* __restrict__ B,
                                                 u16* __restrict__ C) {
  __shared__ u16 lds[65536];  // 128 KB

  const int tid    = threadIdx.x;
  const int lane   = tid & 63;
  const int wv     = tid >> 6;       // 0..7
  const int wr     = wv >> 2;        // 0..1: 64-row slice within quadrant
  const int wc     = wv & 3;         // 0..3: 32-col slice within quadrant
  const int lane15 = lane & 15;
  const int g      = lane >> 4;      // 0..3: 16B k-chunk within K=32 step

  // bijective XCD swizzle, nt-minor (blocks on one XCD share the A panel)
  const int orig = blockIdx.x;
  const int xcd = orig & 7, lin = orig >> 3;
  const int wg = (xcd < R8 ? xcd * (Q8 + 1) : R8 * (Q8 + 1) + (xcd - R8) * Q8) + lin;
  const int mt = wg / NNT, nt = wg % NNT;
  const int tm = mt * BM, tn = nt * BN;

  // staging source offsets (u16 elems; inverse-swizzled global source)
  uint32_t aOff[2][2], bOff[2][2];  // [u][half]
#pragma unroll
  for (int u = 0; u < 2; ++u) {
    const int o    = u * 8192 + tid * 16;          // byte in 16KB half
    const int rloc = o >> 7;                        // local row 0..127
    const int c    = ((o >> 4) & 7) ^ (rloc & 7);   // logical 16B chunk
#pragma unroll
    for (int h = 0; h < 2; ++h) {
      int ra = tm + h * 128 + rloc; if (ra > NTREE - 1) ra = NTREE - 1;
      aOff[u][h] = (uint32_t)ra * HD + c * 8;
      bOff[u][h] = (uint32_t)(tn + h * 128 + rloc) * HD + c * 8;
    }
  }

#define STAGE_A(MH, NB, TT) do {                                               \
    _Pragma("unroll") for (int u = 0; u < 2; ++u)                              \
      __builtin_amdgcn_global_load_lds(                                        \
        (const __attribute__((address_space(1))) void*)(A + aOff[u][MH] + (TT) * BK), \
        (__attribute__((address_space(3))) void*)((char*)lds + (NB) * 32768 +  \
            (MH) * 16384 + u * 8192 + tid * 16),                               \
        16, 0, 0);                                                             \
  } while (0)

#define STAGE_B(NH, NB, TT) do {                                               \
    _Pragma("unroll") for (int u = 0; u < 2; ++u)                              \
      __builtin_amdgcn_global_load_lds(                                        \
        (const __attribute__((address_space(1))) void*)(B + bOff[u][NH] + (TT) * BK), \
        (__attribute__((address_space(3))) void*)((char*)lds + 65536 +         \
            (NB) * 32768 + (NH) * 16384 + u * 8192 + tid * 16),                \
        16, 0, 0);                                                             \
  } while (0)

  f32x4 acc[4][4][2];  // [quadrant][mf][nf]
#pragma unroll
  for (int q = 0; q < 4; ++q)
#pragma unroll
    for (int i = 0; i < 4; ++i)
#pragma unroll
      for (int j = 0; j < 2; ++j) acc[q][i][j] = (f32x4){0.f, 0.f, 0.f, 0.f};

  int colz[2];
  colz[0] = ((0 * 4 + g) ^ (lane15 & 7)) * 8;
  colz[1] = ((1 * 4 + g) ^ (lane15 & 7)) * 8;
  const int aLane = wr * 4096 + lane15 * 64;  // u16; + Mh*8192 + mf*1024
  const int bLane = wc * 2048 + lane15 * 64;  // u16; + Nh*8192 + nf*1024

  bfx8 aF[4][2], bF[2][2];

#define READ_A(MH, BA) do {                                                    \
    _Pragma("unroll") for (int mf = 0; mf < 4; ++mf)                           \
      _Pragma("unroll") for (int ks = 0; ks < 2; ++ks)                         \
        aF[mf][ks] = *(const bfx8*)&lds[(BA) + (MH) * 8192 + aLane +           \
                                        mf * 1024 + colz[ks]];                 \
  } while (0)

#define READ_B(NH, BB) do {                                                    \
    _Pragma("unroll") for (int nf = 0; nf < 2; ++nf)                           \
      _Pragma("unroll") for (int ks = 0; ks < 2; ++ks)                         \
        bF[nf][ks] = *(const bfx8*)&lds[(BB) + (NH) * 8192 + bLane +           \
                                        nf * 1024 + colz[ks]];                 \
  } while (0)

#define MFMA_Q(Q) do {                                                         \
    LGKM(0);                                                                   \
    __builtin_amdgcn_sched_barrier(0);                                         \
    __builtin_amdgcn_s_setprio(1);                                             \
    _Pragma("unroll") for (int mf = 0; mf < 4; ++mf)                           \
      _Pragma("unroll") for (int nf = 0; nf < 2; ++nf)                         \
        _Pragma("unroll") for (int ks = 0; ks < 2; ++ks)                       \
          acc[Q][mf][nf] = __builtin_amdgcn_mfma_f32_16x16x32_bf16(            \
              aF[mf][ks], bF[nf][ks], acc[Q][mf][nf], 0, 0, 0);                \
    __builtin_amdgcn_s_setprio(0);                                             \
  } while (0)

  // prologue: stage tile0 halves in order A0,B0,B1,A1; drain A0,B0; barrier
  STAGE_A(0, 0, 0);
  STAGE_B(0, 0, 0);
  STAGE_B(1, 0, 0);
  STAGE_A(1, 0, 0);
  WAITV(4);
  __builtin_amdgcn_s_barrier();

  for (int t = 0; t < NKT; ++t) {
    const int bA = (t & 1) * 16384;
    const int bB = 32768 + (t & 1) * 16384;
    const int nb = (t + 1) & 1;
    const bool more = (t + 1 < NKT);

    // ph1: q0=(M0,N0). reads A(M0)+B(N0)=12. stage A0(t+1). drain B1(t).
    READ_A(0, bA);
    READ_B(0, bB);
    if (more) STAGE_A(0, nb, t + 1);
    MFMA_Q(0);
    if (more) { WAITV(4); } else { WAITV(2); }
    __builtin_amdgcn_s_barrier();

    // ph2: q1=(M0,N1). reads B(N1)=4 (A in regs). stage B0(t+1). drain A1(t).
    READ_B(1, bB);
    if (more) STAGE_B(0, nb, t + 1);
    MFMA_Q(1);
    if (more) { WAITV(4); } else { WAITV(0); }
    __builtin_amdgcn_s_barrier();

    // ph3: q2=(M1,N1). reads A(M1)=8 (B in regs). stage B1(t+1). no drain.
    READ_A(1, bA);
    if (more) STAGE_B(1, nb, t + 1);
    MFMA_Q(2);
    __builtin_amdgcn_s_barrier();

    // ph4: q3=(M1,N0). reads B(N0)=4. stage A1(t+1). drain A0,B0(t+1).
    READ_B(0, bB);
    if (more) STAGE_A(1, nb, t + 1);
    MFMA_Q(3);
    if (more) { WAITV(4); }
    __builtin_amdgcn_s_barrier();
  }

  // epilogue: q -> (Mh,Nh): 0->(0,0) 1->(0,1) 2->(1,1) 3->(1,0)
  const int r0 = (lane >> 4) * 4, cc = lane15;
  const int qmh[4] = {0, 0, 1, 1}, qnh[4] = {0, 1, 1, 0};
#pragma unroll
  for (int q = 0; q < 4; ++q) {
#pragma unroll
    for (int mf = 0; mf < 4; ++mf) {
#pragma unroll
      for (int nf = 0; nf < 2; ++nf) {
#pragma unroll
        for (int rr = 0; rr < 4; ++rr) {
          const int row = tm + qmh[q] * 128 + wr * 64 + mf * 16 + r0 + rr;
          if (row < NTREE) {
            const int col = tn + qnh[q] * 128 + wc * 32 + nf * 16 + cc;
            C[(size_t)row * GNN + col] = f2bf(acc[q][mf][nf][rr]);
          }
        }
      }
    }
  }
#undef MFMA_Q
#undef READ_A
#undef READ_B
#undef STAGE_A
#undef STAGE_B
}

// ---------------- K2: scores + masked softmax + dag_emb (bf16 out) --------
__global__ __launch_bounds__(512) void k_attn(const u16* __restrict__ PQ,
                                              const u16* __restrict__ Ebf,
                                              const float* __restrict__ b1,
                                              const float* __restrict__ w2,
                                              const float* __restrict__ b2,
                                              const float* __restrict__ masks,
                                              const int* __restrict__ leaves,
                                              const int* __restrict__ anc,
                                              u16* __restrict__ dag) {
  const int n = blockIdx.x;
  const int tid = threadIdx.x, lane = tid & 63, wv = tid >> 6;
  __shared__ float sc[8];
  __shared__ float m_s[8];
  __shared__ int   an_s[8];
  __shared__ int   lv_s[8];
  if (tid < 8) {
    an_s[tid] = anc[n * 8 + tid];
    lv_s[tid] = leaves[n * 8 + tid];
    m_s[tid]  = masks[n * 8 + tid];
  }
  __syncthreads();

  {
    const int a = wv;
    const float mm = m_s[a];
    if (mm == 0.f) {
      if (lane == 0) sc[a] = VNEG;
    } else {
      const int l = lv_s[a], an = an_s[a];
      const u16* pr = PQ + (size_t)l * GNN;
      const u16* qr = PQ + (size_t)an * GNN + HD;
      const int d0 = lane * 12;
      float s = 0.f;
#pragma unroll
      for (int jj = 0; jj < 3; ++jj) {
        const int d = d0 + jj * 4;
        ushort4 pv = *(const ushort4*)(pr + d);
        ushort4 qv = *(const ushort4*)(qr + d);
        float4  bb = *(const float4*)(b1 + d);
        float4  ww = *(const float4*)(w2 + d);
        float v;
        v = fmaxf(bf2f(pv.x) + bf2f(qv.x) + bb.x, 0.f); s += v * ww.x;
        v = fmaxf(bf2f(pv.y) + bf2f(qv.y) + bb.y, 0.f); s += v * ww.y;
        v = fmaxf(bf2f(pv.z) + bf2f(qv.z) + bb.z, 0.f); s += v * ww.z;
        v = fmaxf(bf2f(pv.w) + bf2f(qv.w) + bb.w, 0.f); s += v * ww.w;
      }
#pragma unroll
      for (int off = 32; off > 0; off >>= 1) s += __shfl_down(s, off);
      if (lane == 0) sc[a] = s + b2[0];
    }
  }
  __syncthreads();

  float mx = sc[0];
#pragma unroll
  for (int a = 1; a < 8; ++a) mx = fmaxf(mx, sc[a]);
  float ex[8], den = 0.f;
#pragma unroll
  for (int a = 0; a < 8; ++a) { ex[a] = expf(sc[a] - mx); den += ex[a]; }
  const float inv = 1.0f / den;
  float cf[8];
#pragma unroll
  for (int a = 0; a < 8; ++a) cf[a] = ex[a] * inv * m_s[a];

  if (tid < 384) {
    const int d = tid * 2;
    float a0 = 0.f, a1 = 0.f;
#pragma unroll
    for (int a = 0; a < 8; ++a) {
      const float cfa = cf[a];
      if (cfa != 0.f) {
        const uint32_t w = *(const uint32_t*)(Ebf + (size_t)an_s[a] * HD + d);
        a0 += cfa * bf2f((u16)(w & 0xffffu));
        a1 += cfa * bf2f((u16)(w >> 16));
      }
    }
    const uint32_t packed = (uint32_t)f2bf(a0) | ((uint32_t)f2bf(a1) << 16);
    *(uint32_t*)(dag + (size_t)n * HD + d) = packed;
  }
}

// ---------------- K3: gather dict (bf16) + masked mean pooling ------------
__global__ __launch_bounds__(256) void k_pool(const u16* __restrict__ dag,
                                              const int* __restrict__ ids,
                                              const float* __restrict__ cm,
                                              float* __restrict__ pooled) {
  const int bv = blockIdx.x, tid = threadIdx.x;
  __shared__ int   id_s[48];
  __shared__ float cm_s[48];
  if (tid < 48) { id_s[tid] = ids[bv * 48 + tid]; cm_s[tid] = cm[bv * 48 + tid]; }
  __syncthreads();
  float cnt = 0.f;
  for (int m = 0; m < 48; ++m) cnt += cm_s[m];
  const float scale = 1.0f / fmaxf(cnt, 1.0f);
  if (tid < 192) {
    float4 accv = make_float4(0.f, 0.f, 0.f, 0.f);
    for (int m = 0; m < 48; ++m) {
      const int id = id_s[m];
      const float cv = cm_s[m];
      if (id > 0 && cv != 0.f) {
        ushort4 v = *(const ushort4*)(dag + (size_t)(id - 1) * HD + tid * 4);
        accv.x += cv * bf2f(v.x); accv.y += cv * bf2f(v.y);
        accv.z += cv * bf2f(v.z); accv.w += cv * bf2f(v.w);
      }
    }
    accv.x *= scale; accv.y *= scale; accv.z *= scale; accv.w *= scale;
    *(float4*)(pooled + (size_t)bv * HD + tid * 4) = accv;
  }
}

// ---------------- K4: out = pooled @ wc + bc ------------------------------
__global__ __launch_bounds__(256) void k_out(const float* __restrict__ pooled,
                                             const float* __restrict__ wc,
                                             const float* __restrict__ bc,
                                             float* __restrict__ out) {
  const int b0 = blockIdx.x * TB;
  const int tid = threadIdx.x;
  __shared__ float pl[TB][HD];
  for (int i = tid; i < TB * HD; i += 256) pl[i / HD][i % HD] = pooled[(size_t)b0 * HD + i];
  __syncthreads();
  float a0[TB], a1[TB];
#pragma unroll
  for (int r = 0; r < TB; ++r) { a0[r] = 0.f; a1[r] = 0.f; }
  for (int h = 0; h < HD; ++h) {
    const float w0  = wc[(size_t)h * OUTD + tid];
    const float w1v = wc[(size_t)h * OUTD + tid + 256];
#pragma unroll
    for (int r = 0; r < TB; ++r) { const float p = pl[r][h]; a0[r] += p * w0; a1[r] += p * w1v; }
  }
  const float bc0 = bc[tid], bc1 = bc[tid + 256];
#pragma unroll
  for (int r = 0; r < TB; ++r) {
    out[(size_t)(b0 + r) * OUTD + tid]       = a0[r] + bc0;
    out[(size_t)(b0 + r) * OUTD + tid + 256] = a1[r] + bc1;
  }
}

extern "C" void kernel_launch(void* const* d_in, const int* in_sizes, int n_in,
                              void* d_out, int out_size, void* d_ws, size_t ws_size,
                              hipStream_t stream) {
  const float* E     = (const float*)d_in[0];
  const float* w1    = (const float*)d_in[1];
  const float* b1    = (const float*)d_in[2];
  const float* w2    = (const float*)d_in[3];
  const float* b2    = (const float*)d_in[4];
  const float* wc    = (const float*)d_in[5];
  const float* bc    = (const float*)d_in[6];
  const float* masks = (const float*)d_in[7];
  const float* cm    = (const float*)d_in[8];
  const int*   leaves = (const int*)d_in[9];
  const int*   anc    = (const int*)d_in[10];
  const int*   ids    = (const int*)d_in[11];
  float* out = (float*)d_out;

  if (n_in < 12) return;
  if (in_sizes[0] != NTREE * HD) return;
  if (out_size != NBV * OUTD) return;

  char* ws = (char*)d_ws;
  const size_t szEbf = (size_t)NTREE * HD * 2;
  const size_t szBt  = (size_t)GNN * HD * 2;
  const size_t szPQ  = (size_t)NTREE * GNN * 2;
  const size_t szDag = (size_t)NCODES * HD * 2;
  const size_t szPl  = (size_t)NBV * HD * 4;
  if (ws_size < szEbf + szBt + szPQ + szDag + szPl) return;  // ~196 MB

  u16*   Ebf    = (u16*)ws;            ws += szEbf;
  u16*   Bt     = (u16*)ws;            ws += szBt;
  u16*   PQ     = (u16*)ws;            ws += szPQ;
  u16*   dag    = (u16*)ws;            ws += szDag;
  float* pooled = (float*)ws;          ws += szPl;

  const int nPrep = NBLK_CONV + (GNN * HD + 255) / 256;
  k_prep<<<nPrep, 256, 0, stream>>>(E, Ebf, w1, Bt);
  k_gemm<<<GRID, 512, 0, stream>>>(Ebf, Bt, PQ);
  k_attn<<<NCODES, 512, 0, stream>>>(PQ, Ebf, b1, w2, b2, masks, leaves, anc, dag);
  k_pool<<<NBV, 256, 0, stream>>>(dag, ids, cm, pooled);
  k_out<<<NBV / TB, 256, 0, stream>>>(pooled, wc, bc, out);
}